// Round 23
// baseline (31.422 us; speedup 1.0000x reference)
//
#include <hip/hip_runtime.h>
#include <math.h>

// RandISH v13: R21 + DIAGNOSTIC disjoint-region store doubling (d_ws).
//   out[b, 2n+0] = Al(deg_n, r_b) * y0_norm[n] * P_l(ct)
//   out[b, 2n+1] = Al * cscale[n] * (-1)^deg * Re[(rx + i*ry)^deg]
// rv = vec[b] @ M[n]; rotation preserves |vec|=1 -> no normalization.
//
// PURPOSE: R17's "2x stores free" used SAME-ADDRESS duplicates (mergeable
// in write-combine). This build duplicates every NT store into a DISJOINT
// 64MB region (d_ws, guarded by ws_size) -- unmergeable, HBM must absorb
// 134MB. Outcome separates the final two hypotheses:
//   dur -> 30-40us: pattern write ceiling ~3.4TB/s is REAL -> R21 is the
//     roofline (and the slow dispatch re-enters top-5 counters, giving
//     WRITE_SIZE/hbm_gbps directly).
//   dur ~= 20.5-22: true 2x write headroom -> fixed latency floor binds.
// Either way: next round reverts to R21 and concludes.
//
// Structure (R21/R18 best, 20.35us): block 256 thr = 4 waves, 2 tiles,
// LDS [64][65], grid 2048 = 8 blocks/CU; lane=b, wave w -> bases 8w..8w+7
// (wave-uniform SGPR constants, deg==1 fast path, short recurrences);
// per-wave ascending contiguous 4KB NT store runs.
//
// Re[z^d]: R_k = 2x R_{k-1} - (x^2+y^2) R_{k-2},  R_0=1, R_1=x.
// Al = exp2(-0.5*log2e*d(d+1)*(r+eps))  (0.5/(1/(r+e)+e) ~= 0.5(r+e), 1e-8).

#define NBASIS 32
#define PLEN 10
#define EPSV 1e-8f
#define LOG2E 1.44269504088896340736f
#define ROWD 65    // LDS row stride in dwords (odd -> conflict-free)
#define NT 2       // tiles per block

typedef float f32x4 __attribute__((ext_vector_type(4)));

__global__ __launch_bounds__(256) void randish_kernel(
    const float* __restrict__ vec,        // (B,3)
    const float* __restrict__ rough,      // (B,)
    const float* __restrict__ mats,       // (32,3,3)
    const float* __restrict__ coeffs,     // (32,10) increasing power
    const float* __restrict__ cscale,     // (32,)
    const float* __restrict__ y0n,        // (32,)
    const int*   __restrict__ degs,       // (32,)
    float* __restrict__ out,              // (B,64)
    float* __restrict__ ws,               // diagnostic mirror (may be null)
    int B)
{
    __shared__ float lds[64 * ROWD];      // 16.6 KB -> 8 blocks/CU (grid-capped)

    const int t    = threadIdx.x;         // 0..255
    const int lane = t & 63;              // direction within tile
    const int w    = t >> 6;              // wave id 0..3

    // ---- prefetch BOTH tiles' inputs (independent loads, one window) ----
    float V0[NT], V1[NT], V2[NT], TC[NT];
    int   BB[NT];
#pragma unroll
    for (int it = 0; it < NT; ++it) {
        const int b0 = (blockIdx.x * NT + it) * 64;
        const int b  = b0 + lane;         // B % (64*NT) == 0 -> in range
        BB[it] = b0;
        V0[it] = vec[b * 3 + 0];
        V1[it] = vec[b * 3 + 1];
        V2[it] = vec[b * 3 + 2];
        // Al = exp2( d*(d+1) * tc ),  tc = -0.5*log2e*(r+eps)
        TC[it] = (rough[b] + EPSV) * (-0.5f * LOG2E);
    }

    float* row = &lds[lane * ROWD];

#pragma unroll
    for (int it = 0; it < NT; ++it) {
        const float v0 = V0[it], v1 = V1[it], v2 = V2[it], tc = TC[it];

        // ---- compute tile into LDS ----
#pragma unroll
        for (int j = 0; j < 8; ++j) {
            // n and all derived per-n data are wave-uniform -> SGPRs
            const int n = __builtin_amdgcn_readfirstlane(8 * w + j);
            const int d = __builtin_amdgcn_readfirstlane(degs[n]);

            // rotate (|rv| == 1); mats entries are uniform scalar operands
            const float xh = fmaf(v0, mats[n*9+0], fmaf(v1, mats[n*9+3], v2 * mats[n*9+6]));
            const float yh = fmaf(v0, mats[n*9+1], fmaf(v1, mats[n*9+4], v2 * mats[n*9+7]));
            const float ct = fmaf(v0, mats[n*9+2], fmaf(v1, mats[n*9+5], v2 * mats[n*9+8]));

            const float al = __builtin_amdgcn_exp2f((float)(d * (d + 1)) * tc);

            float y0v, yl1v;
            if (d == 1) {
                // P1(ct) = ct exactly; Re[z^1] = xh; (-1)^1 fold
                y0v  = y0n[n] * ct;
                yl1v = -cscale[n] * xh;
            } else {
                const int par  = d & 1;
                const int base = n * PLEN + par;   // uniform runtime offset
                const float ct2 = ct * ct;

                // Horner with exactly (d>>1)+1 terms (uniform branch tree)
                const int K = d >> 1;              // 1..4 for d in [2,9]
                float v;
                if (K == 1) {
                    v = fmaf(coeffs[base+2], ct2, coeffs[base]);
                } else if (K == 2) {
                    v = fmaf(coeffs[base+4], ct2, coeffs[base+2]);
                    v = fmaf(v, ct2, coeffs[base]);
                } else if (K == 3) {
                    v = fmaf(coeffs[base+6], ct2, coeffs[base+4]);
                    v = fmaf(v, ct2, coeffs[base+2]);
                    v = fmaf(v, ct2, coeffs[base]);
                } else {
                    v = fmaf(coeffs[base+8], ct2, coeffs[base+6]);
                    v = fmaf(v, ct2, coeffs[base+4]);
                    v = fmaf(v, ct2, coeffs[base+2]);
                    v = fmaf(v, ct2, coeffs[base]);
                }
                if (par) v *= ct;                  // uniform branch

                // Re[(xh+i*yh)^d]: d-1 iterations (uniform trip count)
                const float ss  = fmaf(yh, yh, xh * xh);
                const float m2x = xh + xh;
                float Rm2 = 1.0f, Rm1 = xh;
                for (int k = 2; k <= d; ++k) {
                    const float Rk = fmaf(m2x, Rm1, -(ss * Rm2));
                    Rm2 = Rm1;
                    Rm1 = Rk;
                }
                float cs = cscale[n];
                if (par) cs = -cs;                 // fold (-1)^deg, uniform

                y0v  = y0n[n] * v;
                yl1v = cs * Rm1;
            }

            // bank = (lane + 2n) % 32 -> <=2-way across 64 lanes (free)
            row[2 * n + 0] = al * y0v;
            row[2 * n + 1] = al * yl1v;
        }

        __syncthreads();

        // ---- store tile: wave w owns contiguous 4KB quarter, ascending ----
        f32x4 o[4];
#pragma unroll
        for (int p = 0; p < 4; ++p) {
            const int c  = w * 256 + p * 64 + lane;  // ascending per wave
            const int r  = c >> 4;        // source LDS row
            const int c4 = (c & 15) * 4;  // dword column
            const float* src = &lds[r * ROWD + c4];
            o[p] = f32x4{ src[0], src[1], src[2], src[3] };
        }
        f32x4* outp = reinterpret_cast<f32x4*>(out + (size_t)BB[it] * 64);
#pragma unroll
        for (int p = 0; p < 4; ++p)
            __builtin_nontemporal_store(o[p], outp + w * 256 + p * 64 + lane);

        // ---- DIAGNOSTIC: unmergeable duplicate stream into d_ws ----
        if (ws) {
            f32x4* wsp = reinterpret_cast<f32x4*>(ws + (size_t)BB[it] * 64);
#pragma unroll
            for (int p = 0; p < 4; ++p)
                __builtin_nontemporal_store(o[p], wsp + w * 256 + p * 64 + lane);
        }

        if (it + 1 < NT) __syncthreads(); // LDS reuse guard
    }
}

extern "C" void kernel_launch(void* const* d_in, const int* in_sizes, int n_in,
                              void* d_out, int out_size, void* d_ws, size_t ws_size,
                              hipStream_t stream) {
    const float* vec    = (const float*)d_in[0];
    const float* rough  = (const float*)d_in[1];
    const float* mats   = (const float*)d_in[2];
    const float* coeffs = (const float*)d_in[3];
    const float* cscale = (const float*)d_in[4];
    const float* y0n    = (const float*)d_in[5];
    const int*   degs   = (const int*)d_in[6];
    float* out = (float*)d_out;

    const int B = in_sizes[1];            // roughness element count (262144)

    // diagnostic mirror only if scratch can hold the full output stream
    float* ws = (ws_size >= (size_t)out_size * sizeof(float))
                    ? (float*)d_ws : nullptr;

    const int block = 256;                // 4 waves; 2 tiles of 64 directions
    const int grid = B / (64 * NT);       // 2048 blocks -> 8/CU, all resident

    randish_kernel<<<grid, block, 0, stream>>>(vec, rough, mats, coeffs, cscale,
                                               y0n, degs, out, ws, B);
}

// Round 24
// 20.578 us; speedup vs baseline: 1.5270x; 1.5270x over previous
//
#include <hip/hip_runtime.h>
#include <math.h>

// RandISH v14: R21 structure, NT=1 tile/block, grid 4096 -> TWO block
// generations (generation-level compute/store-drain pipelining).
//   out[b, 2n+0] = Al(deg_n, r_b) * y0_norm[n] * P_l(ct)
//   out[b, 2n+1] = Al * cscale[n] * (-1)^deg * Re[(rx + i*ry)^deg]
// rv = vec[b] @ M[n]; rotation preserves |vec|=1 -> no normalization.
//
// R22 diagnostic (disjoint store doubling: +67MB = +11.05us) proved the
// timeline is ADDITIVE: T = F(9.3us, volume-independent) + stores(67MB @
// 6.06TB/s = 11us). Store rate is already ~96% of achievable; the target
// is F. With grid 2048 ALL blocks are co-resident in ONE generation ->
// global compute-then-store ordering; compute can never overlap the drain
// chip-wide (why phase-skew and in-block pipelining were null).
// FIX: grid 4096, one 64-direction tile per block; 8 blocks/CU resident
// -> 2048 concurrent -> TWO generations. Gen-2 entry+loads+compute runs
// WHILE gen-1's NT stores drain (blocks exit after own vmcnt(0), freeing
// slots progressively -> staggered launch, natural decorrelation).
//
// Else identical to R21 (best, 20.35us): 256 thr = 4 waves, LDS [64][65]
// (odd stride, conflict-free), lane=b (coalesced loads), wave w -> bases
// 8w..8w+7 (wave-uniform SGPR constants, uniform branches, deg==1 fast
// path ~58%, short recurrences); per-wave ascending contiguous 4KB NT
// full-line store runs.
//
// Re[z^d]: R_k = 2x R_{k-1} - (x^2+y^2) R_{k-2},  R_0=1, R_1=x.
// Al = exp2(-0.5*log2e*d(d+1)*(r+eps))  (0.5/(1/(r+e)+e) ~= 0.5(r+e), 1e-8).

#define NBASIS 32
#define PLEN 10
#define EPSV 1e-8f
#define LOG2E 1.44269504088896340736f
#define ROWD 65    // LDS row stride in dwords (odd -> conflict-free)

typedef float f32x4 __attribute__((ext_vector_type(4)));

__global__ __launch_bounds__(256) void randish_kernel(
    const float* __restrict__ vec,        // (B,3)
    const float* __restrict__ rough,      // (B,)
    const float* __restrict__ mats,       // (32,3,3)
    const float* __restrict__ coeffs,     // (32,10) increasing power
    const float* __restrict__ cscale,     // (32,)
    const float* __restrict__ y0n,        // (32,)
    const int*   __restrict__ degs,       // (32,)
    float* __restrict__ out,              // (B,64)
    int B)
{
    __shared__ float lds[64 * ROWD];      // 16.6 KB -> 8 blocks/CU resident

    const int t    = threadIdx.x;         // 0..255
    const int lane = t & 63;              // direction within tile
    const int w    = t >> 6;              // wave id 0..3

    const int b0 = blockIdx.x * 64;
    const int b  = b0 + lane;             // B % 64 == 0 -> always in range

    const float v0 = vec[b * 3 + 0];
    const float v1 = vec[b * 3 + 1];
    const float v2 = vec[b * 3 + 2];
    // Al = exp2( d*(d+1) * tc ),  tc = -0.5*log2e*(r+eps)
    const float tc = (rough[b] + EPSV) * (-0.5f * LOG2E);

    float* row = &lds[lane * ROWD];

    // ---- compute tile into LDS ----
#pragma unroll
    for (int j = 0; j < 8; ++j) {
        // n and all derived per-n data are wave-uniform -> SGPRs
        const int n = __builtin_amdgcn_readfirstlane(8 * w + j);
        const int d = __builtin_amdgcn_readfirstlane(degs[n]);

        // rotate (|rv| == 1); mats entries are uniform scalar operands
        const float xh = fmaf(v0, mats[n*9+0], fmaf(v1, mats[n*9+3], v2 * mats[n*9+6]));
        const float yh = fmaf(v0, mats[n*9+1], fmaf(v1, mats[n*9+4], v2 * mats[n*9+7]));
        const float ct = fmaf(v0, mats[n*9+2], fmaf(v1, mats[n*9+5], v2 * mats[n*9+8]));

        const float al = __builtin_amdgcn_exp2f((float)(d * (d + 1)) * tc);

        float y0v, yl1v;
        if (d == 1) {
            // P1(ct) = ct exactly; Re[z^1] = xh; (-1)^1 fold
            y0v  = y0n[n] * ct;
            yl1v = -cscale[n] * xh;
        } else {
            const int par  = d & 1;
            const int base = n * PLEN + par;   // uniform runtime offset
            const float ct2 = ct * ct;

            // Horner with exactly (d>>1)+1 terms (uniform branch tree)
            const int K = d >> 1;              // 1..4 for d in [2,9]
            float v;
            if (K == 1) {
                v = fmaf(coeffs[base+2], ct2, coeffs[base]);
            } else if (K == 2) {
                v = fmaf(coeffs[base+4], ct2, coeffs[base+2]);
                v = fmaf(v, ct2, coeffs[base]);
            } else if (K == 3) {
                v = fmaf(coeffs[base+6], ct2, coeffs[base+4]);
                v = fmaf(v, ct2, coeffs[base+2]);
                v = fmaf(v, ct2, coeffs[base]);
            } else {
                v = fmaf(coeffs[base+8], ct2, coeffs[base+6]);
                v = fmaf(v, ct2, coeffs[base+4]);
                v = fmaf(v, ct2, coeffs[base+2]);
                v = fmaf(v, ct2, coeffs[base]);
            }
            if (par) v *= ct;                  // uniform branch

            // Re[(xh+i*yh)^d]: d-1 iterations (uniform trip count)
            const float ss  = fmaf(yh, yh, xh * xh);
            const float m2x = xh + xh;
            float Rm2 = 1.0f, Rm1 = xh;
            for (int k = 2; k <= d; ++k) {
                const float Rk = fmaf(m2x, Rm1, -(ss * Rm2));
                Rm2 = Rm1;
                Rm1 = Rk;
            }
            float cs = cscale[n];
            if (par) cs = -cs;                 // fold (-1)^deg, uniform

            y0v  = y0n[n] * v;
            yl1v = cs * Rm1;
        }

        // bank = (lane + 2n) % 32 -> <=2-way across 64 lanes (free)
        row[2 * n + 0] = al * y0v;
        row[2 * n + 1] = al * yl1v;
    }

    __syncthreads();

    // ---- store tile: wave w owns contiguous 4KB quarter, ascending;
    //      4 x 1KB full-line NT runs; block exits after drain, freeing
    //      its slot for a generation-2 block (compute overlaps drain) ----
    f32x4 o[4];
#pragma unroll
    for (int p = 0; p < 4; ++p) {
        const int c  = w * 256 + p * 64 + lane;  // ascending per wave
        const int r  = c >> 4;            // source LDS row
        const int c4 = (c & 15) * 4;      // dword column
        const float* src = &lds[r * ROWD + c4];
        o[p] = f32x4{ src[0], src[1], src[2], src[3] };
    }
    f32x4* outp = reinterpret_cast<f32x4*>(out + (size_t)b0 * 64);
#pragma unroll
    for (int p = 0; p < 4; ++p)
        __builtin_nontemporal_store(o[p], outp + w * 256 + p * 64 + lane);
}

extern "C" void kernel_launch(void* const* d_in, const int* in_sizes, int n_in,
                              void* d_out, int out_size, void* d_ws, size_t ws_size,
                              hipStream_t stream) {
    const float* vec    = (const float*)d_in[0];
    const float* rough  = (const float*)d_in[1];
    const float* mats   = (const float*)d_in[2];
    const float* coeffs = (const float*)d_in[3];
    const float* cscale = (const float*)d_in[4];
    const float* y0n    = (const float*)d_in[5];
    const int*   degs   = (const int*)d_in[6];
    float* out = (float*)d_out;

    const int B = in_sizes[1];            // roughness element count (262144)
    const int block = 256;                // 4 waves; ONE 64-direction tile
    const int grid = B / 64;              // 4096 blocks -> 2 generations

    randish_kernel<<<grid, block, 0, stream>>>(vec, rough, mats, coeffs, cscale,
                                               y0n, degs, out, B);
}